// Round 3
// baseline (451.191 us; speedup 1.0000x reference)
//
#include <hip/hip_runtime.h>
#include <stdint.h>

#define NN 50000
#define NE 800000
#define NB1 196    // (NN+255)/256 blocks for scan phases
#define NBK 1563   // (NN+31)/32 dst buckets of 32 nodes

typedef __attribute__((ext_vector_type(8))) short short8;
typedef __attribute__((ext_vector_type(4))) float floatx4;

__device__ __forceinline__ uint16_t f2bf(float f){
  union { float f; uint32_t u; } c; c.f = f;
  uint32_t u = c.u + 0x7FFFu + ((c.u >> 16) & 1u);
  return (uint16_t)(u >> 16);
}
__device__ __forceinline__ float bflo(uint32_t v){
  union { uint32_t u; float f; } c; c.u = v << 16; return c.f;
}
__device__ __forceinline__ float bfhi(uint32_t v){
  union { uint32_t u; float f; } c; c.u = v & 0xFFFF0000u; return c.f;
}
__device__ __forceinline__ float bfs(uint16_t v){
  union { uint32_t u; float f; } c; c.u = ((uint32_t)v) << 16; return c.f;
}

// ---------------- fused preprocessing ----------------
#define B_CVT 6250   // NN*128/4 / 256
#define B_DEG 3125   // NE/256
#define B_PIN 64
#define B_P0  128
#define B_P1  128
#define B_P2  64

__device__ __forceinline__ void pack_one(int idx, const float* __restrict__ wl,
                                         const float* __restrict__ wr,
                                         uint16_t* __restrict__ bp,
                                         int ncolL, int ncolR, int NT){
  int j = idx & 7, lane = (idx >> 3) & 63, rest = idx >> 9;
  int nt = rest % NT, kt = rest / NT;
  int k = kt * 32 + ((lane >> 4) << 3) + j;
  int n = nt * 16 + (lane & 15);
  float v = (n < ncolL) ? wl[k * ncolL + n] : wr[k * ncolR + (n - ncolL)];
  bp[idx] = f2bf(v);
}

__global__ __launch_bounds__(256) void k_prep(const float* __restrict__ x, uint2* __restrict__ xb,
                                              const int* __restrict__ ei, int* __restrict__ deg,
                                              const float* __restrict__ w_in,
                                              const float* __restrict__ w_l0, const float* __restrict__ w_r0,
                                              const float* __restrict__ w_l1, const float* __restrict__ w_r1,
                                              const float* __restrict__ w_l2, const float* __restrict__ w_r2,
                                              uint16_t* __restrict__ bpIn, uint16_t* __restrict__ bp0,
                                              uint16_t* __restrict__ bp1, uint16_t* __restrict__ bp2){
  int b = blockIdx.x;
  if (b < B_CVT){
    int i = b * 256 + threadIdx.x;
    if (i < NN * 128 / 4){
      float4 v = ((const float4*)x)[i];
      uint32_t lo = (uint32_t)f2bf(v.x) | ((uint32_t)f2bf(v.y) << 16);
      uint32_t hi = (uint32_t)f2bf(v.z) | ((uint32_t)f2bf(v.w) << 16);
      xb[i] = make_uint2(lo, hi);
    }
    return;
  }
  b -= B_CVT;
  if (b < B_DEG){
    int e = b * 256 + threadIdx.x;
    if (e < NE) atomicAdd(&deg[ei[NE + e]], 1);
    return;
  }
  b -= B_DEG;
  if (b < B_PIN){ pack_one(b * 256 + threadIdx.x, w_in, w_in, bpIn, 128, 0, 8); return; }
  b -= B_PIN;
  if (b < B_P0){ pack_one(b * 256 + threadIdx.x, w_l0, w_r0, bp0, 128, 128, 16); return; }
  b -= B_P0;
  if (b < B_P1){ pack_one(b * 256 + threadIdx.x, w_l1, w_r1, bp1, 128, 128, 16); return; }
  b -= B_P1;
  pack_one(b * 256 + threadIdx.x, w_l2, w_r2, bp2, 64, 64, 8);
}

// ---------------- parallel 3-phase scan ----------------
__global__ __launch_bounds__(256) void k_scan1(const int* __restrict__ deg, int* __restrict__ bsum){
  int i = blockIdx.x * 256 + threadIdx.x;
  int v = (i < NN) ? deg[i] : 0;
  #pragma unroll
  for (int off = 32; off; off >>= 1) v += __shfl_down(v, off, 64);
  __shared__ int s[4];
  if ((threadIdx.x & 63) == 0) s[threadIdx.x >> 6] = v;
  __syncthreads();
  if (threadIdx.x == 0) bsum[blockIdx.x] = s[0] + s[1] + s[2] + s[3];
}

__global__ __launch_bounds__(256) void k_scan2(const int* __restrict__ bsum, int* __restrict__ boff){
  __shared__ int s[256];
  int t = threadIdx.x;
  int v = (t < NB1) ? bsum[t] : 0;
  s[t] = v;
  __syncthreads();
  #pragma unroll
  for (int off = 1; off < 256; off <<= 1){
    int u = (t >= off) ? s[t - off] : 0;
    __syncthreads();
    s[t] += u;
    __syncthreads();
  }
  if (t < NB1) boff[t] = s[t] - v;  // exclusive
}

// also seeds per-bucket cursors ccur[b] = rowp[b*32] (exclusive prefix at bucket start)
__global__ __launch_bounds__(256) void k_scan3(const int* __restrict__ deg, const int* __restrict__ boff,
                                               int* __restrict__ rowp, int* __restrict__ ccur){
  __shared__ int s[256];
  int t = threadIdx.x;
  int i = blockIdx.x * 256 + t;
  int v = (i < NN) ? deg[i] : 0;
  s[t] = v;
  __syncthreads();
  #pragma unroll
  for (int off = 1; off < 256; off <<= 1){
    int u = (t >= off) ? s[t - off] : 0;
    __syncthreads();
    s[t] += u;
    __syncthreads();
  }
  int base = boff[blockIdx.x];
  if (i < NN){
    rowp[i + 1] = base + s[t];
    if ((i & 31) == 0) ccur[i >> 5] = base + s[t] - v;  // exclusive prefix at node i
  }
  if (i == 0) rowp[0] = 0;
}

// ---------------- two-level edge bucketing ----------------
// pass 1: append (src | dlow<<16) into per-bucket sequential streams
__global__ __launch_bounds__(256) void k_part(const int* __restrict__ ei, int* __restrict__ ccur,
                                              uint32_t* __restrict__ pairs){
  int e = blockIdx.x * 256 + threadIdx.x;
  if (e < NE){
    int d = ei[NE + e];
    int s = ei[e];
    int pos = atomicAdd(&ccur[d >> 5], 1);
    pairs[pos] = (uint32_t)s | ((uint32_t)(d & 31) << 16);
  }
}

// pass 2: one block per bucket; LDS cursors; all traffic within a ~2KB region
__global__ __launch_bounds__(256) void k_fill(const uint32_t* __restrict__ pairs,
                                              const int* __restrict__ rowp, int* __restrict__ colx){
  __shared__ int lrow[33];
  __shared__ int lcur[32];
  int b = blockIdx.x;
  int n0 = b * 32;
  int nNodes = min(32, NN - n0);
  if (threadIdx.x < nNodes + 1) lrow[threadIdx.x] = rowp[n0 + threadIdx.x];
  if (threadIdx.x < 32) lcur[threadIdx.x] = 0;
  __syncthreads();
  int base = lrow[0];
  int cnt = lrow[nNodes] - base;
  for (int i = threadIdx.x; i < cnt; i += 256){
    uint32_t v = pairs[base + i];
    int dlow = v >> 16;
    int pos = atomicAdd(&lcur[dlow], 1);
    colx[lrow[dlow] + pos] = (int)(v & 0xFFFFu);
  }
}

// ------------- GEMM: A[N,128]bf16 @ Bp[128, NCOL] -> epilogue -------------
template<int NTW, int MODE>
__global__ __launch_bounds__(256) void k_gemm(const uint16_t* __restrict__ A, const uint16_t* __restrict__ Bp,
                                              const float* __restrict__ bias,
                                              uint16_t* __restrict__ o0, uint16_t* __restrict__ o1,
                                              float* __restrict__ o2){
  const int NTT = 4 * NTW;
  int lane = threadIdx.x & 63;
  int wave = threadIdx.x >> 6;
  short8 bfrag[4][NTW];
  #pragma unroll
  for (int kt = 0; kt < 4; ++kt)
    #pragma unroll
    for (int n = 0; n < NTW; ++n)
      bfrag[kt][n] = *(const short8*)(Bp + (size_t)((kt * NTT + wave * NTW + n) * 64 + lane) * 8);

  int m = lane & 15, quad = lane >> 4;
  const int nrt = NN / 16;
  for (int rt = blockIdx.x; rt < nrt; rt += gridDim.x){
    int r0 = rt * 16;
    const uint16_t* arow = A + (size_t)(r0 + m) * 128 + quad * 8;
    short8 af[4];
    #pragma unroll
    for (int kt = 0; kt < 4; ++kt) af[kt] = *(const short8*)(arow + kt * 32);
    floatx4 acc[NTW];
    #pragma unroll
    for (int n = 0; n < NTW; ++n) acc[n] = (floatx4){0.f, 0.f, 0.f, 0.f};
    #pragma unroll
    for (int kt = 0; kt < 4; ++kt)
      #pragma unroll
      for (int n = 0; n < NTW; ++n)
        acc[n] = __builtin_amdgcn_mfma_f32_16x16x32_bf16(af[kt], bfrag[kt][n], acc[n], 0, 0, 0);

    int rbase = r0 + quad * 4;
    #pragma unroll
    for (int n = 0; n < NTW; ++n){
      int c = (wave * NTW + n) * 16 + m;
      #pragma unroll
      for (int i = 0; i < 4; ++i){
        float v = acc[n][i];
        int row = rbase + i;
        if (MODE == 0){
          float h = v + bias[c];
          o0[(size_t)row * 128 + c] = f2bf(fmaxf(h, 0.f));
          o1[(size_t)row * 128 + c] = f2bf(0.2f * h);
        } else if (MODE == 1){
          if (c < 128) o0[(size_t)row * 128 + c] = f2bf(v);
          else         o1[(size_t)row * 128 + (c - 128)] = f2bf(v + bias[c - 128]);
        } else {
          if (c < 64) o0[(size_t)row * 64 + c] = f2bf(v);
          else        o2[(size_t)row * 64 + (c - 64)] = v + bias[c - 64];
        }
      }
    }
  }
}

// ------------- aggregation (pull, CSR): one wave per node -------------
__global__ __launch_bounds__(256) void agg_mid(const uint32_t* __restrict__ yb, const uint32_t* __restrict__ zb,
                                               const uint32_t* __restrict__ resb,
                                               const int* __restrict__ colx, const int* __restrict__ rowp,
                                               uint32_t* __restrict__ hb_out){
  int wid = blockIdx.x * 4 + (threadIdx.x >> 6);
  if (wid >= NN) return;
  int lane = threadIdx.x & 63;
  int e0 = rowp[wid], e1 = rowp[wid + 1];
  float a0 = 0.f, a1 = 0.f;
  int e = e0;
  for (; e + 4 <= e1; e += 4){
    int s0 = colx[e], s1 = colx[e + 1], s2 = colx[e + 2], s3 = colx[e + 3];
    uint32_t v0 = yb[(size_t)s0 * 64 + lane];
    uint32_t v1 = yb[(size_t)s1 * 64 + lane];
    uint32_t v2 = yb[(size_t)s2 * 64 + lane];
    uint32_t v3 = yb[(size_t)s3 * 64 + lane];
    a0 += bflo(v0) + bflo(v1) + bflo(v2) + bflo(v3);
    a1 += bfhi(v0) + bfhi(v1) + bfhi(v2) + bfhi(v3);
  }
  for (; e < e1; ++e){
    uint32_t v = yb[(size_t)colx[e] * 64 + lane];
    a0 += bflo(v); a1 += bfhi(v);
  }
  int deg = e1 - e0;
  float inv = deg > 0 ? 1.f / (float)deg : 0.f;
  uint32_t zv = zb[(size_t)wid * 64 + lane];
  uint32_t rv = resb[(size_t)wid * 64 + lane];
  float v0 = fmaxf(a0 * inv + bflo(zv), 0.f) + bflo(rv);
  float v1 = fmaxf(a1 * inv + bfhi(zv), 0.f) + bfhi(rv);
  hb_out[(size_t)wid * 64 + lane] = (uint32_t)f2bf(v0) | ((uint32_t)f2bf(v1) << 16);
}

__global__ __launch_bounds__(256) void agg_out(const uint16_t* __restrict__ yb2, const float* __restrict__ z2,
                                               const int* __restrict__ colx, const int* __restrict__ rowp,
                                               float* __restrict__ out){
  int wid = blockIdx.x * 4 + (threadIdx.x >> 6);
  if (wid >= NN) return;
  int lane = threadIdx.x & 63;
  int e0 = rowp[wid], e1 = rowp[wid + 1];
  float a = 0.f;
  int e = e0;
  for (; e + 4 <= e1; e += 4){
    int s0 = colx[e], s1 = colx[e + 1], s2 = colx[e + 2], s3 = colx[e + 3];
    a += bfs(yb2[(size_t)s0 * 64 + lane]) + bfs(yb2[(size_t)s1 * 64 + lane])
       + bfs(yb2[(size_t)s2 * 64 + lane]) + bfs(yb2[(size_t)s3 * 64 + lane]);
  }
  for (; e < e1; ++e) a += bfs(yb2[(size_t)colx[e] * 64 + lane]);
  int deg = e1 - e0;
  float inv = deg > 0 ? 1.f / (float)deg : 0.f;
  float v = a * inv + z2[(size_t)wid * 64 + lane];
  float mx = v;
  #pragma unroll
  for (int off = 32; off; off >>= 1) mx = fmaxf(mx, __shfl_xor(mx, off, 64));
  float ex = __expf(v - mx);
  float sm = ex;
  #pragma unroll
  for (int off = 32; off; off >>= 1) sm += __shfl_xor(sm, off, 64);
  out[(size_t)wid * 64 + lane] = (v - mx) - __logf(sm);
}

extern "C" void kernel_launch(void* const* d_in, const int* in_sizes, int n_in,
                              void* d_out, int out_size, void* d_ws, size_t ws_size,
                              hipStream_t stream){
  const float* x    = (const float*)d_in[0];
  const int*   ei   = (const int*)d_in[1];
  const float* w_in = (const float*)d_in[2];
  const float* b_in = (const float*)d_in[3];
  const float* w_l0 = (const float*)d_in[4];
  const float* w_r0 = (const float*)d_in[5];
  const float* b0   = (const float*)d_in[6];
  const float* w_l1 = (const float*)d_in[7];
  const float* w_r1 = (const float*)d_in[8];
  const float* b1   = (const float*)d_in[9];
  const float* w_l2 = (const float*)d_in[10];
  const float* w_r2 = (const float*)d_in[11];
  const float* b2   = (const float*)d_in[12];
  float* out = (float*)d_out;

  char* ws = (char*)d_ws;
  size_t off = 0;
  auto take = [&](size_t bytes) -> char* {
    char* p = ws + off;
    off = (off + bytes + 1023) & ~(size_t)1023;
    return p;
  };
  uint16_t* hb   = (uint16_t*)take((size_t)NN * 128 * 2);
  uint16_t* resb = (uint16_t*)take((size_t)NN * 128 * 2);
  uint16_t* yb   = (uint16_t*)take((size_t)NN * 128 * 2);
  uint16_t* zb   = (uint16_t*)take((size_t)NN * 128 * 2);
  int* colx   = (int*)take((size_t)NE * 4);
  uint32_t* pairs = (uint32_t*)take((size_t)NE * 4);
  int* deg    = (int*)take((size_t)NN * 4);
  int* ccur   = (int*)take((size_t)NBK * 4);
  int* rowp   = (int*)take((size_t)(NN + 1) * 4);
  int* bsum   = (int*)take((size_t)NB1 * 4);
  int* boff   = (int*)take((size_t)NB1 * 4);
  uint16_t* BpIn = (uint16_t*)take(128 * 128 * 2);
  uint16_t* Bp0  = (uint16_t*)take(128 * 256 * 2);
  uint16_t* Bp1  = (uint16_t*)take(128 * 256 * 2);
  uint16_t* Bp2  = (uint16_t*)take(128 * 128 * 2);
  (void)ws_size; (void)in_sizes; (void)n_in; (void)out_size;

  hipMemsetAsync(deg, 0, (size_t)NN * 4, stream);

  // fused: cvt + deg + all weight packs
  k_prep<<<B_CVT + B_DEG + B_PIN + B_P0 + B_P1 + B_P2, 256, 0, stream>>>(
      x, (uint2*)yb, ei, deg, w_in, w_l0, w_r0, w_l1, w_r1, w_l2, w_r2, BpIn, Bp0, Bp1, Bp2);

  // parallel scan -> rowp (+ bucket cursors), then two-level bucket sort
  k_scan1<<<NB1, 256, 0, stream>>>(deg, bsum);
  k_scan2<<<1, 256, 0, stream>>>(bsum, boff);
  k_scan3<<<NB1, 256, 0, stream>>>(deg, boff, rowp, ccur);
  k_part<<<B_DEG, 256, 0, stream>>>(ei, ccur, pairs);
  k_fill<<<NBK, 256, 0, stream>>>(pairs, rowp, colx);

  // lin_in: inp/h
  k_gemm<2, 0><<<1024, 256, 0, stream>>>(yb, BpIn, b_in, hb, resb, nullptr);

  // conv0
  k_gemm<4, 1><<<1024, 256, 0, stream>>>(hb, Bp0, b0, yb, zb, nullptr);
  agg_mid<<<NN / 4, 256, 0, stream>>>((const uint32_t*)yb, (const uint32_t*)zb, (const uint32_t*)resb,
                                      colx, rowp, (uint32_t*)hb);
  // conv1
  k_gemm<4, 1><<<1024, 256, 0, stream>>>(hb, Bp1, b1, yb, zb, nullptr);
  agg_mid<<<NN / 4, 256, 0, stream>>>((const uint32_t*)yb, (const uint32_t*)zb, (const uint32_t*)resb,
                                      colx, rowp, (uint32_t*)hb);
  // conv2 + log_softmax
  k_gemm<2, 2><<<1024, 256, 0, stream>>>(hb, Bp2, b2, yb, nullptr, (float*)zb);
  agg_out<<<NN / 4, 256, 0, stream>>>(yb, (const float*)zb, colx, rowp, out);
}

// Round 4
// 369.022 us; speedup vs baseline: 1.2227x; 1.2227x over previous
//
#include <hip/hip_runtime.h>
#include <stdint.h>

#define NN 50000
#define NE 800000
#define NB1 196    // (NN+255)/256 blocks for scan phases

typedef __attribute__((ext_vector_type(8))) short short8;
typedef __attribute__((ext_vector_type(4))) float floatx4;

__device__ __forceinline__ uint16_t f2bf(float f){
  union { float f; uint32_t u; } c; c.f = f;
  uint32_t u = c.u + 0x7FFFu + ((c.u >> 16) & 1u);
  return (uint16_t)(u >> 16);
}
__device__ __forceinline__ float bflo(uint32_t v){
  union { uint32_t u; float f; } c; c.u = v << 16; return c.f;
}
__device__ __forceinline__ float bfhi(uint32_t v){
  union { uint32_t u; float f; } c; c.u = v & 0xFFFF0000u; return c.f;
}
__device__ __forceinline__ float bfs(uint16_t v){
  union { uint32_t u; float f; } c; c.u = ((uint32_t)v) << 16; return c.f;
}

// ---------------- fused preprocessing ----------------
#define B_CVT 6250   // NN*128/4 / 256
#define B_DEG 3125   // NE/256
#define B_PIN 64
#define B_P0  128
#define B_P1  128
#define B_P2  64

__device__ __forceinline__ void pack_one(int idx, const float* __restrict__ wl,
                                         const float* __restrict__ wr,
                                         uint16_t* __restrict__ bp,
                                         int ncolL, int ncolR, int NT){
  int j = idx & 7, lane = (idx >> 3) & 63, rest = idx >> 9;
  int nt = rest % NT, kt = rest / NT;
  int k = kt * 32 + ((lane >> 4) << 3) + j;
  int n = nt * 16 + (lane & 15);
  float v = (n < ncolL) ? wl[k * ncolL + n] : wr[k * ncolR + (n - ncolL)];
  bp[idx] = f2bf(v);
}

// deg counters are line-padded: deg[i*16] is node i's counter (one 64B line each)
__global__ __launch_bounds__(256) void k_prep(const float* __restrict__ x, uint2* __restrict__ xb,
                                              const int* __restrict__ ei, int* __restrict__ deg,
                                              const float* __restrict__ w_in,
                                              const float* __restrict__ w_l0, const float* __restrict__ w_r0,
                                              const float* __restrict__ w_l1, const float* __restrict__ w_r1,
                                              const float* __restrict__ w_l2, const float* __restrict__ w_r2,
                                              uint16_t* __restrict__ bpIn, uint16_t* __restrict__ bp0,
                                              uint16_t* __restrict__ bp1, uint16_t* __restrict__ bp2){
  int b = blockIdx.x;
  if (b < B_CVT){
    int i = b * 256 + threadIdx.x;
    if (i < NN * 128 / 4){
      float4 v = ((const float4*)x)[i];
      uint32_t lo = (uint32_t)f2bf(v.x) | ((uint32_t)f2bf(v.y) << 16);
      uint32_t hi = (uint32_t)f2bf(v.z) | ((uint32_t)f2bf(v.w) << 16);
      xb[i] = make_uint2(lo, hi);
    }
    return;
  }
  b -= B_CVT;
  if (b < B_DEG){
    int e = b * 256 + threadIdx.x;
    if (e < NE) atomicAdd(&deg[ei[NE + e] * 16], 1);
    return;
  }
  b -= B_DEG;
  if (b < B_PIN){ pack_one(b * 256 + threadIdx.x, w_in, w_in, bpIn, 128, 0, 8); return; }
  b -= B_PIN;
  if (b < B_P0){ pack_one(b * 256 + threadIdx.x, w_l0, w_r0, bp0, 128, 128, 16); return; }
  b -= B_P0;
  if (b < B_P1){ pack_one(b * 256 + threadIdx.x, w_l1, w_r1, bp1, 128, 128, 16); return; }
  b -= B_P1;
  pack_one(b * 256 + threadIdx.x, w_l2, w_r2, bp2, 64, 64, 8);
}

// ---------------- parallel 3-phase scan (deg is line-padded) ----------------
__global__ __launch_bounds__(256) void k_scan1(const int* __restrict__ deg, int* __restrict__ bsum){
  int i = blockIdx.x * 256 + threadIdx.x;
  int v = (i < NN) ? deg[i * 16] : 0;
  #pragma unroll
  for (int off = 32; off; off >>= 1) v += __shfl_down(v, off, 64);
  __shared__ int s[4];
  if ((threadIdx.x & 63) == 0) s[threadIdx.x >> 6] = v;
  __syncthreads();
  if (threadIdx.x == 0) bsum[blockIdx.x] = s[0] + s[1] + s[2] + s[3];
}

__global__ __launch_bounds__(256) void k_scan2(const int* __restrict__ bsum, int* __restrict__ boff){
  __shared__ int s[256];
  int t = threadIdx.x;
  int v = (t < NB1) ? bsum[t] : 0;
  s[t] = v;
  __syncthreads();
  #pragma unroll
  for (int off = 1; off < 256; off <<= 1){
    int u = (t >= off) ? s[t - off] : 0;
    __syncthreads();
    s[t] += u;
    __syncthreads();
  }
  if (t < NB1) boff[t] = s[t] - v;  // exclusive
}

__global__ __launch_bounds__(256) void k_scan3(const int* __restrict__ deg, const int* __restrict__ boff,
                                               int* __restrict__ rowp){
  __shared__ int s[256];
  int t = threadIdx.x;
  int i = blockIdx.x * 256 + t;
  int v = (i < NN) ? deg[i * 16] : 0;
  s[t] = v;
  __syncthreads();
  #pragma unroll
  for (int off = 1; off < 256; off <<= 1){
    int u = (t >= off) ? s[t - off] : 0;
    __syncthreads();
    s[t] += u;
    __syncthreads();
  }
  int base = boff[blockIdx.x];
  if (i < NN) rowp[i + 1] = base + s[t];
  if (i == 0) rowp[0] = 0;
}

// scatter with line-padded cursors: cursor[d*16]
__global__ __launch_bounds__(256) void k_scatter(const int* __restrict__ ei, const int* __restrict__ rowp,
                                                 int* __restrict__ cursor, int* __restrict__ colx){
  int e = blockIdx.x * 256 + threadIdx.x;
  if (e < NE){
    int d = ei[NE + e];
    int pos = atomicAdd(&cursor[d * 16], 1);
    colx[rowp[d] + pos] = ei[e];
  }
}

// ------------- GEMM: A[N,128]bf16 @ Bp[128, NCOL] -> epilogue -------------
template<int NTW, int MODE>
__global__ __launch_bounds__(256) void k_gemm(const uint16_t* __restrict__ A, const uint16_t* __restrict__ Bp,
                                              const float* __restrict__ bias,
                                              uint16_t* __restrict__ o0, uint16_t* __restrict__ o1,
                                              float* __restrict__ o2){
  const int NTT = 4 * NTW;
  int lane = threadIdx.x & 63;
  int wave = threadIdx.x >> 6;
  short8 bfrag[4][NTW];
  #pragma unroll
  for (int kt = 0; kt < 4; ++kt)
    #pragma unroll
    for (int n = 0; n < NTW; ++n)
      bfrag[kt][n] = *(const short8*)(Bp + (size_t)((kt * NTT + wave * NTW + n) * 64 + lane) * 8);

  int m = lane & 15, quad = lane >> 4;
  const int nrt = NN / 16;
  for (int rt = blockIdx.x; rt < nrt; rt += gridDim.x){
    int r0 = rt * 16;
    const uint16_t* arow = A + (size_t)(r0 + m) * 128 + quad * 8;
    short8 af[4];
    #pragma unroll
    for (int kt = 0; kt < 4; ++kt) af[kt] = *(const short8*)(arow + kt * 32);
    floatx4 acc[NTW];
    #pragma unroll
    for (int n = 0; n < NTW; ++n) acc[n] = (floatx4){0.f, 0.f, 0.f, 0.f};
    #pragma unroll
    for (int kt = 0; kt < 4; ++kt)
      #pragma unroll
      for (int n = 0; n < NTW; ++n)
        acc[n] = __builtin_amdgcn_mfma_f32_16x16x32_bf16(af[kt], bfrag[kt][n], acc[n], 0, 0, 0);

    int rbase = r0 + quad * 4;
    #pragma unroll
    for (int n = 0; n < NTW; ++n){
      int c = (wave * NTW + n) * 16 + m;
      #pragma unroll
      for (int i = 0; i < 4; ++i){
        float v = acc[n][i];
        int row = rbase + i;
        if (MODE == 0){
          float h = v + bias[c];
          o0[(size_t)row * 128 + c] = f2bf(fmaxf(h, 0.f));
          o1[(size_t)row * 128 + c] = f2bf(0.2f * h);
        } else if (MODE == 1){
          if (c < 128) o0[(size_t)row * 128 + c] = f2bf(v);
          else         o1[(size_t)row * 128 + (c - 128)] = f2bf(v + bias[c - 128]);
        } else {
          if (c < 64) o0[(size_t)row * 64 + c] = f2bf(v);
          else        o2[(size_t)row * 64 + (c - 64)] = v + bias[c - 64];
        }
      }
    }
  }
}

// ------------- aggregation (pull, CSR): one wave per node -------------
__global__ __launch_bounds__(256) void agg_mid(const uint32_t* __restrict__ yb, const uint32_t* __restrict__ zb,
                                               const uint32_t* __restrict__ resb,
                                               const int* __restrict__ colx, const int* __restrict__ rowp,
                                               uint32_t* __restrict__ hb_out){
  int wid = blockIdx.x * 4 + (threadIdx.x >> 6);
  if (wid >= NN) return;
  int lane = threadIdx.x & 63;
  int e0 = rowp[wid], e1 = rowp[wid + 1];
  float a0 = 0.f, a1 = 0.f;
  int e = e0;
  for (; e + 4 <= e1; e += 4){
    int s0 = colx[e], s1 = colx[e + 1], s2 = colx[e + 2], s3 = colx[e + 3];
    uint32_t v0 = yb[(size_t)s0 * 64 + lane];
    uint32_t v1 = yb[(size_t)s1 * 64 + lane];
    uint32_t v2 = yb[(size_t)s2 * 64 + lane];
    uint32_t v3 = yb[(size_t)s3 * 64 + lane];
    a0 += bflo(v0) + bflo(v1) + bflo(v2) + bflo(v3);
    a1 += bfhi(v0) + bfhi(v1) + bfhi(v2) + bfhi(v3);
  }
  for (; e < e1; ++e){
    uint32_t v = yb[(size_t)colx[e] * 64 + lane];
    a0 += bflo(v); a1 += bfhi(v);
  }
  int deg = e1 - e0;
  float inv = deg > 0 ? 1.f / (float)deg : 0.f;
  uint32_t zv = zb[(size_t)wid * 64 + lane];
  uint32_t rv = resb[(size_t)wid * 64 + lane];
  float v0 = fmaxf(a0 * inv + bflo(zv), 0.f) + bflo(rv);
  float v1 = fmaxf(a1 * inv + bfhi(zv), 0.f) + bfhi(rv);
  hb_out[(size_t)wid * 64 + lane] = (uint32_t)f2bf(v0) | ((uint32_t)f2bf(v1) << 16);
}

__global__ __launch_bounds__(256) void agg_out(const uint16_t* __restrict__ yb2, const float* __restrict__ z2,
                                               const int* __restrict__ colx, const int* __restrict__ rowp,
                                               float* __restrict__ out){
  int wid = blockIdx.x * 4 + (threadIdx.x >> 6);
  if (wid >= NN) return;
  int lane = threadIdx.x & 63;
  int e0 = rowp[wid], e1 = rowp[wid + 1];
  float a = 0.f;
  int e = e0;
  for (; e + 4 <= e1; e += 4){
    int s0 = colx[e], s1 = colx[e + 1], s2 = colx[e + 2], s3 = colx[e + 3];
    a += bfs(yb2[(size_t)s0 * 64 + lane]) + bfs(yb2[(size_t)s1 * 64 + lane])
       + bfs(yb2[(size_t)s2 * 64 + lane]) + bfs(yb2[(size_t)s3 * 64 + lane]);
  }
  for (; e < e1; ++e) a += bfs(yb2[(size_t)colx[e] * 64 + lane]);
  int deg = e1 - e0;
  float inv = deg > 0 ? 1.f / (float)deg : 0.f;
  float v = a * inv + z2[(size_t)wid * 64 + lane];
  float mx = v;
  #pragma unroll
  for (int off = 32; off; off >>= 1) mx = fmaxf(mx, __shfl_xor(mx, off, 64));
  float ex = __expf(v - mx);
  float sm = ex;
  #pragma unroll
  for (int off = 32; off; off >>= 1) sm += __shfl_xor(sm, off, 64);
  out[(size_t)wid * 64 + lane] = (v - mx) - __logf(sm);
}

extern "C" void kernel_launch(void* const* d_in, const int* in_sizes, int n_in,
                              void* d_out, int out_size, void* d_ws, size_t ws_size,
                              hipStream_t stream){
  const float* x    = (const float*)d_in[0];
  const int*   ei   = (const int*)d_in[1];
  const float* w_in = (const float*)d_in[2];
  const float* b_in = (const float*)d_in[3];
  const float* w_l0 = (const float*)d_in[4];
  const float* w_r0 = (const float*)d_in[5];
  const float* b0   = (const float*)d_in[6];
  const float* w_l1 = (const float*)d_in[7];
  const float* w_r1 = (const float*)d_in[8];
  const float* b1   = (const float*)d_in[9];
  const float* w_l2 = (const float*)d_in[10];
  const float* w_r2 = (const float*)d_in[11];
  const float* b2   = (const float*)d_in[12];
  float* out = (float*)d_out;

  char* ws = (char*)d_ws;
  size_t off = 0;
  auto take = [&](size_t bytes) -> char* {
    char* p = ws + off;
    off = (off + bytes + 1023) & ~(size_t)1023;
    return p;
  };
  uint16_t* hb   = (uint16_t*)take((size_t)NN * 128 * 2);
  uint16_t* resb = (uint16_t*)take((size_t)NN * 128 * 2);
  uint16_t* yb   = (uint16_t*)take((size_t)NN * 128 * 2);
  uint16_t* zb   = (uint16_t*)take((size_t)NN * 128 * 2);
  int* colx   = (int*)take((size_t)NE * 4);
  int* atomslab = (int*)take((size_t)2 * NN * 16 * 4);  // line-padded deg | cursor
  int* deg    = atomslab;            // deg[i*16]
  int* cursor = atomslab + NN * 16;  // cursor[i*16]
  int* rowp   = (int*)take((size_t)(NN + 1) * 4);
  int* bsum   = (int*)take((size_t)NB1 * 4);
  int* boff   = (int*)take((size_t)NB1 * 4);
  uint16_t* BpIn = (uint16_t*)take(128 * 128 * 2);
  uint16_t* Bp0  = (uint16_t*)take(128 * 256 * 2);
  uint16_t* Bp1  = (uint16_t*)take(128 * 256 * 2);
  uint16_t* Bp2  = (uint16_t*)take(128 * 128 * 2);
  (void)ws_size; (void)in_sizes; (void)n_in; (void)out_size;

  hipMemsetAsync(atomslab, 0, (size_t)2 * NN * 16 * 4, stream);

  // fused: cvt + deg histogram (line-padded) + all weight packs
  k_prep<<<B_CVT + B_DEG + B_PIN + B_P0 + B_P1 + B_P2, 256, 0, stream>>>(
      x, (uint2*)yb, ei, deg, w_in, w_l0, w_r0, w_l1, w_r1, w_l2, w_r2, BpIn, Bp0, Bp1, Bp2);

  // parallel scan -> rowp, then direct scatter (line-padded cursors)
  k_scan1<<<NB1, 256, 0, stream>>>(deg, bsum);
  k_scan2<<<1, 256, 0, stream>>>(bsum, boff);
  k_scan3<<<NB1, 256, 0, stream>>>(deg, boff, rowp);
  k_scatter<<<B_DEG, 256, 0, stream>>>(ei, rowp, cursor, colx);

  // lin_in: inp/h
  k_gemm<2, 0><<<1024, 256, 0, stream>>>(yb, BpIn, b_in, hb, resb, nullptr);

  // conv0
  k_gemm<4, 1><<<1024, 256, 0, stream>>>(hb, Bp0, b0, yb, zb, nullptr);
  agg_mid<<<NN / 4, 256, 0, stream>>>((const uint32_t*)yb, (const uint32_t*)zb, (const uint32_t*)resb,
                                      colx, rowp, (uint32_t*)hb);
  // conv1
  k_gemm<4, 1><<<1024, 256, 0, stream>>>(hb, Bp1, b1, yb, zb, nullptr);
  agg_mid<<<NN / 4, 256, 0, stream>>>((const uint32_t*)yb, (const uint32_t*)zb, (const uint32_t*)resb,
                                      colx, rowp, (uint32_t*)hb);
  // conv2 + log_softmax
  k_gemm<2, 2><<<1024, 256, 0, stream>>>(hb, Bp2, b2, yb, nullptr, (float*)zb);
  agg_out<<<NN / 4, 256, 0, stream>>>(yb, (const float*)zb, colx, rowp, out);
}

// Round 5
// 335.368 us; speedup vs baseline: 1.3454x; 1.1003x over previous
//
#include <hip/hip_runtime.h>
#include <stdint.h>

#define NN 50000
#define NE 800000
#define NBIN 196   // dst buckets of 256 nodes (dst >> 8)
#define ABLK 98    // blocks in hist/bin passes
#define EPB 8164   // edges per block: 98*8164 >= NE
#define BCAP 6144  // per-bucket LDS capacity (avg 4082, sigma ~64)

typedef __attribute__((ext_vector_type(8))) short short8;
typedef __attribute__((ext_vector_type(4))) float floatx4;

__device__ __forceinline__ uint16_t f2bf(float f){
  union { float f; uint32_t u; } c; c.f = f;
  uint32_t u = c.u + 0x7FFFu + ((c.u >> 16) & 1u);
  return (uint16_t)(u >> 16);
}
__device__ __forceinline__ float bflo(uint32_t v){
  union { uint32_t u; float f; } c; c.u = v << 16; return c.f;
}
__device__ __forceinline__ float bfhi(uint32_t v){
  union { uint32_t u; float f; } c; c.u = v & 0xFFFF0000u; return c.f;
}
__device__ __forceinline__ float bfs(uint16_t v){
  union { uint32_t u; float f; } c; c.u = ((uint32_t)v) << 16; return c.f;
}

// ---------------- fused preprocessing (cvt + weight packs; no histogram) ----------------
#define B_CVT 6250   // NN*128/4 / 256
#define B_PIN 64
#define B_P0  128
#define B_P1  128
#define B_P2  64

__device__ __forceinline__ void pack_one(int idx, const float* __restrict__ wl,
                                         const float* __restrict__ wr,
                                         uint16_t* __restrict__ bp,
                                         int ncolL, int ncolR, int NT){
  int j = idx & 7, lane = (idx >> 3) & 63, rest = idx >> 9;
  int nt = rest % NT, kt = rest / NT;
  int k = kt * 32 + ((lane >> 4) << 3) + j;
  int n = nt * 16 + (lane & 15);
  float v = (n < ncolL) ? wl[k * ncolL + n] : wr[k * ncolR + (n - ncolL)];
  bp[idx] = f2bf(v);
}

__global__ __launch_bounds__(256) void k_prep(const float* __restrict__ x, uint2* __restrict__ xb,
                                              const float* __restrict__ w_in,
                                              const float* __restrict__ w_l0, const float* __restrict__ w_r0,
                                              const float* __restrict__ w_l1, const float* __restrict__ w_r1,
                                              const float* __restrict__ w_l2, const float* __restrict__ w_r2,
                                              uint16_t* __restrict__ bpIn, uint16_t* __restrict__ bp0,
                                              uint16_t* __restrict__ bp1, uint16_t* __restrict__ bp2){
  int b = blockIdx.x;
  if (b < B_CVT){
    int i = b * 256 + threadIdx.x;
    if (i < NN * 128 / 4){
      float4 v = ((const float4*)x)[i];
      uint32_t lo = (uint32_t)f2bf(v.x) | ((uint32_t)f2bf(v.y) << 16);
      uint32_t hi = (uint32_t)f2bf(v.z) | ((uint32_t)f2bf(v.w) << 16);
      xb[i] = make_uint2(lo, hi);
    }
    return;
  }
  b -= B_CVT;
  if (b < B_PIN){ pack_one(b * 256 + threadIdx.x, w_in, w_in, bpIn, 128, 0, 8); return; }
  b -= B_PIN;
  if (b < B_P0){ pack_one(b * 256 + threadIdx.x, w_l0, w_r0, bp0, 128, 128, 16); return; }
  b -= B_P0;
  if (b < B_P1){ pack_one(b * 256 + threadIdx.x, w_l1, w_r1, bp1, 128, 128, 16); return; }
  b -= B_P1;
  pack_one(b * 256 + threadIdx.x, w_l2, w_r2, bp2, 64, 64, 8);
}

// ---------------- pass A1: per-block bucket histogram ----------------
__global__ __launch_bounds__(256) void k_hist(const int* __restrict__ ei, int* __restrict__ histG){
  __shared__ int h[NBIN];
  for (int i = threadIdx.x; i < NBIN; i += 256) h[i] = 0;
  __syncthreads();
  int base = blockIdx.x * EPB;
  for (int k = threadIdx.x; k < EPB; k += 256){
    int e = base + k;
    if (e < NE) atomicAdd(&h[ei[NE + e] >> 8], 1);
  }
  __syncthreads();
  for (int i = threadIdx.x; i < NBIN; i += 256) histG[i * ABLK + blockIdx.x] = h[i];
}

// ---------------- pass A2: scan (bin-major over blocks) + bin bases ----------------
__global__ __launch_bounds__(256) void k_scanG(int* __restrict__ histG, int* __restrict__ binStart){
  __shared__ int s[256];
  int t = threadIdx.x;
  int tot = 0;
  if (t < NBIN){
    for (int b = 0; b < ABLK; ++b){
      int v = histG[t * ABLK + b];
      histG[t * ABLK + b] = tot;
      tot += v;
    }
  }
  s[t] = (t < NBIN) ? tot : 0;
  __syncthreads();
  #pragma unroll
  for (int off = 1; off < 256; off <<= 1){
    int u = (t >= off) ? s[t - off] : 0;
    __syncthreads();
    s[t] += u;
    __syncthreads();
  }
  int excl = s[t] - ((t < NBIN) ? tot : 0);
  if (t < NBIN){
    binStart[t] = excl;
    for (int b = 0; b < ABLK; ++b) histG[t * ABLK + b] += excl;
  }
  if (t == 0) binStart[NBIN] = NE;
}

// ---------------- pass A3: LDS bin-sort, contiguous-run writes ----------------
__global__ __launch_bounds__(256) void k_bin(const int* __restrict__ ei, const int* __restrict__ histG,
                                             uint32_t* __restrict__ pairs){
  __shared__ int h[NBIN], loc[NBIN], cur[NBIN], gof[NBIN];
  __shared__ int sc[256];
  __shared__ uint32_t st[EPB];
  int t = threadIdx.x;
  int base = blockIdx.x * EPB;
  for (int i = t; i < NBIN; i += 256) h[i] = 0;
  __syncthreads();
  for (int k = t; k < EPB; k += 256){
    int e = base + k;
    if (e < NE) atomicAdd(&h[ei[NE + e] >> 8], 1);
  }
  __syncthreads();
  int cv = (t < NBIN) ? h[t] : 0;
  sc[t] = cv;
  __syncthreads();
  #pragma unroll
  for (int off = 1; off < 256; off <<= 1){
    int u = (t >= off) ? sc[t - off] : 0;
    __syncthreads();
    sc[t] += u;
    __syncthreads();
  }
  if (t < NBIN){
    int excl = sc[t] - cv;
    loc[t] = excl;
    cur[t] = excl;
    gof[t] = histG[t * ABLK + blockIdx.x];
  }
  __syncthreads();
  for (int k = t; k < EPB; k += 256){
    int e = base + k;
    if (e < NE){
      int d = ei[NE + e];
      int s0 = ei[e];
      int pos = atomicAdd(&cur[d >> 8], 1);
      st[pos] = (uint32_t)s0 | ((uint32_t)d << 16);
    }
  }
  __syncthreads();
  int cnt = min(EPB, NE - base);
  for (int k = t; k < cnt; k += 256){
    uint32_t v = st[k];
    int bin = (int)(v >> 24);
    pairs[gof[bin] + (k - loc[bin])] = v;
  }
}

// ---------------- pass B: per-bucket counting sort -> rowp + colx(u16) ----------------
__global__ __launch_bounds__(256) void k_csr(const uint32_t* __restrict__ pairs, const int* __restrict__ binStart,
                                             int* __restrict__ rowp, uint16_t* __restrict__ colx){
  __shared__ uint32_t pl[BCAP];
  __shared__ uint16_t stg[BCAP];
  __shared__ int h[256], sc[256];
  int i = blockIdx.x, t = threadIdx.x;
  int p0 = binStart[i], p1 = binStart[i + 1];
  int cnt = min(p1 - p0, BCAP);
  for (int k = t; k < cnt; k += 256) pl[k] = pairs[p0 + k];
  h[t] = 0;
  __syncthreads();
  for (int k = t; k < cnt; k += 256) atomicAdd(&h[(pl[k] >> 16) & 255], 1);
  __syncthreads();
  int cv = h[t];
  sc[t] = cv;
  __syncthreads();
  #pragma unroll
  for (int off = 1; off < 256; off <<= 1){
    int u = (t >= off) ? sc[t - off] : 0;
    __syncthreads();
    sc[t] += u;
    __syncthreads();
  }
  int excl = sc[t] - cv;
  int n0 = i << 8;
  int nc = min(256, NN - n0);
  if (t < nc) rowp[n0 + t] = p0 + excl;
  if (i == NBIN - 1 && t == 0) rowp[NN] = NE;
  h[t] = excl;   // becomes cursor
  __syncthreads();
  for (int k = t; k < cnt; k += 256){
    uint32_t v = pl[k];
    int pos = atomicAdd(&h[(v >> 16) & 255], 1);
    stg[pos] = (uint16_t)(v & 0xFFFFu);
  }
  __syncthreads();
  for (int k = t; k < cnt; k += 256) colx[p0 + k] = stg[k];
}

// ------------- GEMM: A[N,128]bf16 @ Bp[128, NCOL] -> epilogue -------------
template<int NTW, int MODE>
__global__ __launch_bounds__(256) void k_gemm(const uint16_t* __restrict__ A, const uint16_t* __restrict__ Bp,
                                              const float* __restrict__ bias,
                                              uint16_t* __restrict__ o0, uint16_t* __restrict__ o1,
                                              float* __restrict__ o2){
  const int NTT = 4 * NTW;
  int lane = threadIdx.x & 63;
  int wave = threadIdx.x >> 6;
  short8 bfrag[4][NTW];
  #pragma unroll
  for (int kt = 0; kt < 4; ++kt)
    #pragma unroll
    for (int n = 0; n < NTW; ++n)
      bfrag[kt][n] = *(const short8*)(Bp + (size_t)((kt * NTT + wave * NTW + n) * 64 + lane) * 8);

  int m = lane & 15, quad = lane >> 4;
  const int nrt = NN / 16;
  for (int rt = blockIdx.x; rt < nrt; rt += gridDim.x){
    int r0 = rt * 16;
    const uint16_t* arow = A + (size_t)(r0 + m) * 128 + quad * 8;
    short8 af[4];
    #pragma unroll
    for (int kt = 0; kt < 4; ++kt) af[kt] = *(const short8*)(arow + kt * 32);
    floatx4 acc[NTW];
    #pragma unroll
    for (int n = 0; n < NTW; ++n) acc[n] = (floatx4){0.f, 0.f, 0.f, 0.f};
    #pragma unroll
    for (int kt = 0; kt < 4; ++kt)
      #pragma unroll
      for (int n = 0; n < NTW; ++n)
        acc[n] = __builtin_amdgcn_mfma_f32_16x16x32_bf16(af[kt], bfrag[kt][n], acc[n], 0, 0, 0);

    int rbase = r0 + quad * 4;
    #pragma unroll
    for (int n = 0; n < NTW; ++n){
      int c = (wave * NTW + n) * 16 + m;
      #pragma unroll
      for (int i = 0; i < 4; ++i){
        float v = acc[n][i];
        int row = rbase + i;
        if (MODE == 0){
          float h = v + bias[c];
          o0[(size_t)row * 128 + c] = f2bf(fmaxf(h, 0.f));
          o1[(size_t)row * 128 + c] = f2bf(0.2f * h);
        } else if (MODE == 1){
          if (c < 128) o0[(size_t)row * 128 + c] = f2bf(v);
          else         o1[(size_t)row * 128 + (c - 128)] = f2bf(v + bias[c - 128]);
        } else {
          if (c < 64) o0[(size_t)row * 64 + c] = f2bf(v);
          else        o2[(size_t)row * 64 + (c - 64)] = v + bias[c - 64];
        }
      }
    }
  }
}

// ------------- aggregation (pull, CSR): one wave per node -------------
__global__ __launch_bounds__(256) void agg_mid(const uint32_t* __restrict__ yb, const uint32_t* __restrict__ zb,
                                               const uint32_t* __restrict__ resb,
                                               const uint16_t* __restrict__ colx, const int* __restrict__ rowp,
                                               uint32_t* __restrict__ hb_out){
  int wid = blockIdx.x * 4 + (threadIdx.x >> 6);
  if (wid >= NN) return;
  int lane = threadIdx.x & 63;
  int e0 = rowp[wid], e1 = rowp[wid + 1];
  float a0 = 0.f, a1 = 0.f;
  int e = e0;
  for (; e + 4 <= e1; e += 4){
    int s0 = colx[e], s1 = colx[e + 1], s2 = colx[e + 2], s3 = colx[e + 3];
    uint32_t v0 = yb[(size_t)s0 * 64 + lane];
    uint32_t v1 = yb[(size_t)s1 * 64 + lane];
    uint32_t v2 = yb[(size_t)s2 * 64 + lane];
    uint32_t v3 = yb[(size_t)s3 * 64 + lane];
    a0 += bflo(v0) + bflo(v1) + bflo(v2) + bflo(v3);
    a1 += bfhi(v0) + bfhi(v1) + bfhi(v2) + bfhi(v3);
  }
  for (; e < e1; ++e){
    uint32_t v = yb[(size_t)colx[e] * 64 + lane];
    a0 += bflo(v); a1 += bfhi(v);
  }
  int deg = e1 - e0;
  float inv = deg > 0 ? 1.f / (float)deg : 0.f;
  uint32_t zv = zb[(size_t)wid * 64 + lane];
  uint32_t rv = resb[(size_t)wid * 64 + lane];
  float v0 = fmaxf(a0 * inv + bflo(zv), 0.f) + bflo(rv);
  float v1 = fmaxf(a1 * inv + bfhi(zv), 0.f) + bfhi(rv);
  hb_out[(size_t)wid * 64 + lane] = (uint32_t)f2bf(v0) | ((uint32_t)f2bf(v1) << 16);
}

__global__ __launch_bounds__(256) void agg_out(const uint16_t* __restrict__ yb2, const float* __restrict__ z2,
                                               const uint16_t* __restrict__ colx, const int* __restrict__ rowp,
                                               float* __restrict__ out){
  int wid = blockIdx.x * 4 + (threadIdx.x >> 6);
  if (wid >= NN) return;
  int lane = threadIdx.x & 63;
  int e0 = rowp[wid], e1 = rowp[wid + 1];
  float a = 0.f;
  int e = e0;
  for (; e + 4 <= e1; e += 4){
    int s0 = colx[e], s1 = colx[e + 1], s2 = colx[e + 2], s3 = colx[e + 3];
    a += bfs(yb2[(size_t)s0 * 64 + lane]) + bfs(yb2[(size_t)s1 * 64 + lane])
       + bfs(yb2[(size_t)s2 * 64 + lane]) + bfs(yb2[(size_t)s3 * 64 + lane]);
  }
  for (; e < e1; ++e) a += bfs(yb2[(size_t)colx[e] * 64 + lane]);
  int deg = e1 - e0;
  float inv = deg > 0 ? 1.f / (float)deg : 0.f;
  float v = a * inv + z2[(size_t)wid * 64 + lane];
  float mx = v;
  #pragma unroll
  for (int off = 32; off; off >>= 1) mx = fmaxf(mx, __shfl_xor(mx, off, 64));
  float ex = __expf(v - mx);
  float sm = ex;
  #pragma unroll
  for (int off = 32; off; off >>= 1) sm += __shfl_xor(sm, off, 64);
  out[(size_t)wid * 64 + lane] = (v - mx) - __logf(sm);
}

extern "C" void kernel_launch(void* const* d_in, const int* in_sizes, int n_in,
                              void* d_out, int out_size, void* d_ws, size_t ws_size,
                              hipStream_t stream){
  const float* x    = (const float*)d_in[0];
  const int*   ei   = (const int*)d_in[1];
  const float* w_in = (const float*)d_in[2];
  const float* b_in = (const float*)d_in[3];
  const float* w_l0 = (const float*)d_in[4];
  const float* w_r0 = (const float*)d_in[5];
  const float* b0   = (const float*)d_in[6];
  const float* w_l1 = (const float*)d_in[7];
  const float* w_r1 = (const float*)d_in[8];
  const float* b1   = (const float*)d_in[9];
  const float* w_l2 = (const float*)d_in[10];
  const float* w_r2 = (const float*)d_in[11];
  const float* b2   = (const float*)d_in[12];
  float* out = (float*)d_out;

  char* ws = (char*)d_ws;
  size_t off = 0;
  auto take = [&](size_t bytes) -> char* {
    char* p = ws + off;
    off = (off + bytes + 1023) & ~(size_t)1023;
    return p;
  };
  uint16_t* hb   = (uint16_t*)take((size_t)NN * 128 * 2);
  uint16_t* resb = (uint16_t*)take((size_t)NN * 128 * 2);
  uint16_t* yb   = (uint16_t*)take((size_t)NN * 128 * 2);
  uint16_t* zb   = (uint16_t*)take((size_t)NN * 128 * 2);
  uint32_t* pairs = (uint32_t*)take((size_t)NE * 4);
  uint16_t* colx  = (uint16_t*)take((size_t)NE * 2);
  int* histG    = (int*)take((size_t)NBIN * ABLK * 4);
  int* binStart = (int*)take((size_t)(NBIN + 1) * 4);
  int* rowp     = (int*)take((size_t)(NN + 1) * 4);
  uint16_t* BpIn = (uint16_t*)take(128 * 128 * 2);
  uint16_t* Bp0  = (uint16_t*)take(128 * 256 * 2);
  uint16_t* Bp1  = (uint16_t*)take(128 * 256 * 2);
  uint16_t* Bp2  = (uint16_t*)take(128 * 128 * 2);
  (void)ws_size; (void)in_sizes; (void)n_in; (void)out_size;

  // fused: cvt + all weight packs
  k_prep<<<B_CVT + B_PIN + B_P0 + B_P1 + B_P2, 256, 0, stream>>>(
      x, (uint2*)yb, w_in, w_l0, w_r0, w_l1, w_r1, w_l2, w_r2, BpIn, Bp0, Bp1, Bp2);

  // CSR build: histogram -> scan -> LDS bin-sort -> per-bucket counting sort
  k_hist<<<ABLK, 256, 0, stream>>>(ei, histG);
  k_scanG<<<1, 256, 0, stream>>>(histG, binStart);
  k_bin<<<ABLK, 256, 0, stream>>>(ei, histG, pairs);
  k_csr<<<NBIN, 256, 0, stream>>>(pairs, binStart, rowp, colx);

  // lin_in: inp/h
  k_gemm<2, 0><<<1024, 256, 0, stream>>>(yb, BpIn, b_in, hb, resb, nullptr);

  // conv0
  k_gemm<4, 1><<<1024, 256, 0, stream>>>(hb, Bp0, b0, yb, zb, nullptr);
  agg_mid<<<NN / 4, 256, 0, stream>>>((const uint32_t*)yb, (const uint32_t*)zb, (const uint32_t*)resb,
                                      colx, rowp, (uint32_t*)hb);
  // conv1
  k_gemm<4, 1><<<1024, 256, 0, stream>>>(hb, Bp1, b1, yb, zb, nullptr);
  agg_mid<<<NN / 4, 256, 0, stream>>>((const uint32_t*)yb, (const uint32_t*)zb, (const uint32_t*)resb,
                                      colx, rowp, (uint32_t*)hb);
  // conv2 + log_softmax
  k_gemm<2, 2><<<1024, 256, 0, stream>>>(hb, Bp2, b2, yb, nullptr, (float*)zb);
  agg_out<<<NN / 4, 256, 0, stream>>>(yb, (const float*)zb, colx, rowp, out);
}